// Round 2
// baseline (673.680 us; speedup 1.0000x reference)
//
#include <hip/hip_runtime.h>
#include <math.h>

// n is fixed by the problem: angles has n(n-1)/2 = 2016 -> n = 64.
#define N 64
#define NPAIRS (N * (N - 1) / 2)  // 2016
#define NSEG 8
#define SEGLEN (NPAIRS / NSEG)    // 252
#define STJ 68                    // padded stride (floats) for transposed segment tile

// Pairs before row t in np.triu_indices(64, k=1) row-major order.
constexpr int k0row(int t) { return t * 63 - t * (t - 1) / 2; }
// Row containing rotation index k.
constexpr int rowOf(int k) {
  int t = 0;
  while (t < 62 && k0row(t + 1) <= k) ++t;
  return t;
}

// ---------------------------------------------------------------------------
// Apply rotations k in [W*SEGLEN, (W+1)*SEGLEN) to this lane's column.
// Loop bounds are tight compile-time constants (no guards inside a giant
// unroll): outer t-range is constexpr, inner b-range folds once t is
// unrolled. ~252 rotations of straight-line code per instantiation, so
// col[] indices are compile-time -> col[] stays in VGPRs (no scratch).
// ---------------------------------------------------------------------------
template <int W>
__device__ __forceinline__ void apply_seg(float col[N], const float2* cs) {
  constexpr int LO = W * SEGLEN;
  constexpr int HI = LO + SEGLEN;
  constexpr int tLo = rowOf(LO);
  constexpr int tHi = rowOf(HI - 1);
#pragma unroll
  for (int t = tLo; t <= tHi; ++t) {
    const int bLo = (t == tLo) ? (t + 1 + (LO - k0row(t))) : (t + 1);
    const int bHi = (t == tHi) ? (t + 1 + (HI - k0row(t))) : N;
#pragma unroll
    for (int b = bLo; b < bHi; ++b) {
      const int k = k0row(t) + (b - (t + 1));
      float2 p = cs[k];  // p.x = cos, p.y = sin
      float rt = col[t];
      float rb = col[b];
      col[t] = fmaf(p.x, rt, -p.y * rb);
      col[b] = fmaf(p.y, rt, p.x * rb);
    }
  }
}

// ---------------------------------------------------------------------------
// Kernel 1: build R^T (scaled by mus) from the Givens angle sequence.
// 512 threads (8 waves), 1 block.
//   Phase 1: wave w computes segment product S_w (one column per lane,
//            registers, compile-time unrolled -- 1/8 of the serial chain).
//   Phase 2: sequential combine P <- S_w * P for w = 1..7 using all 512
//            threads (verified correct in the previous round).
// Output layout: RT[j*64 + i] = mus[i] * R[i][j].
// ---------------------------------------------------------------------------
__global__ __launch_bounds__(512) void build_r_kernel(
    const float* __restrict__ angles, const float* __restrict__ mus,
    float* __restrict__ RT) {
  __shared__ float2 cs[NPAIRS];   // 16128 B
  __shared__ float P[N * N];      // running product, P[k*64 + j]   (16384 B)
  __shared__ float ST[N * STJ];   // S_w transposed: ST[k*STJ + i]  (17408 B)

  const int tid = threadIdx.x;
  const int lane = tid & 63;
  const int wid = tid >> 6;

  // Parallel sincos across all 512 threads.
  for (int k = tid; k < NPAIRS; k += 512) {
    float s, c;
    sincosf(angles[k], &s, &c);
    cs[k] = make_float2(c, s);
  }
  __syncthreads();

  // ---- Phase 1: per-wave segment product, one column per lane ----
  float col[N];
#pragma unroll
  for (int i = 0; i < N; ++i) col[i] = (i == lane) ? 1.0f : 0.0f;

  switch (wid) {
    case 0: apply_seg<0>(col, cs); break;
    case 1: apply_seg<1>(col, cs); break;
    case 2: apply_seg<2>(col, cs); break;
    case 3: apply_seg<3>(col, cs); break;
    case 4: apply_seg<4>(col, cs); break;
    case 5: apply_seg<5>(col, cs); break;
    case 6: apply_seg<6>(col, cs); break;
    case 7: apply_seg<7>(col, cs); break;
  }

  // ---- Phase 2: P <- S_0, then P <- S_w * P for w = 1..7 ----
  if (wid == 0) {
#pragma unroll
    for (int i = 0; i < N; ++i) P[i * N + lane] = col[i];  // stride-1: conflict-free
  }
  __syncthreads();

  const int i0 = wid * 8;
  float acc[8];
#pragma unroll
  for (int u = 0; u < 8; ++u) acc[u] = 0.0f;

  for (int w = 1; w < NSEG; ++w) {
    // Wave w dumps its segment, transposed: ST[k][i] = S_w[i][k].
    if (wid == w) {
#pragma unroll
      for (int u = 0; u < N / 4; ++u) {
        *(float4*)&ST[lane * STJ + u * 4] =
            make_float4(col[4 * u], col[4 * u + 1], col[4 * u + 2], col[4 * u + 3]);
      }
    }
    __syncthreads();

    // C = S_w * P ; thread computes C[i0..i0+8)[lane].
#pragma unroll
    for (int u = 0; u < 8; ++u) acc[u] = 0.0f;
#pragma unroll 4
    for (int k = 0; k < N; ++k) {
      float bkj = P[k * N + lane];                        // stride-1: conflict-free
      float4 a0 = *(const float4*)&ST[k * STJ + i0];      // uniform: broadcast
      float4 a1 = *(const float4*)&ST[k * STJ + i0 + 4];  // uniform: broadcast
      acc[0] = fmaf(a0.x, bkj, acc[0]);
      acc[1] = fmaf(a0.y, bkj, acc[1]);
      acc[2] = fmaf(a0.z, bkj, acc[2]);
      acc[3] = fmaf(a0.w, bkj, acc[3]);
      acc[4] = fmaf(a1.x, bkj, acc[4]);
      acc[5] = fmaf(a1.y, bkj, acc[5]);
      acc[6] = fmaf(a1.z, bkj, acc[6]);
      acc[7] = fmaf(a1.w, bkj, acc[7]);
    }
    __syncthreads();
#pragma unroll
    for (int u = 0; u < 8; ++u) P[(i0 + u) * N + lane] = acc[u];
    __syncthreads();
  }

  // acc holds final R rows [i0, i0+8) of column `lane`.
  // RT[j][i] = mus[i] * R[i][j]
#pragma unroll
  for (int u = 0; u < 8; ++u) {
    const int i = i0 + u;
    RT[lane * N + i] = mus[i] * acc[u];
  }
}

// ---------------------------------------------------------------------------
// Kernel 2: out[i][j] = sum_k R[i][k] * X[k][j].
// TWO adjacent columns per thread (float2 loads/stores, 8 B/lane coalesced);
// 64 float2 accumulators in VGPRs. R reads are wave-uniform global loads ->
// scalar s_load into SGPRs (proven by round-0's VGPR count of 68); each R
// value now feeds 2 FMAs, halving the R-delivery overhead per FLOP.
// No LDS (the round-1 LDS broadcast path serialized on the LDS pipe).
// ---------------------------------------------------------------------------
__global__ __launch_bounds__(256, 3) void apply_r_kernel(
    const float* __restrict__ X, const float* __restrict__ RT,
    float* __restrict__ out, int m) {
  const int j = (blockIdx.x * 256 + threadIdx.x) * 2;
  if (j >= m) return;

  if (j + 1 < m) {
    // main path: column pair (j, j+1)
    float2 acc[N];
#pragma unroll
    for (int i = 0; i < N; ++i) acc[i] = make_float2(0.0f, 0.0f);

#pragma unroll 4
    for (int k = 0; k < N; ++k) {
      const float2 x = *(const float2*)(X + (size_t)k * m + j);
      const float4* r4 = (const float4*)(RT + k * N);
#pragma unroll
      for (int ii = 0; ii < N / 4; ++ii) {
        float4 r = r4[ii];
        acc[ii * 4 + 0].x = fmaf(r.x, x.x, acc[ii * 4 + 0].x);
        acc[ii * 4 + 0].y = fmaf(r.x, x.y, acc[ii * 4 + 0].y);
        acc[ii * 4 + 1].x = fmaf(r.y, x.x, acc[ii * 4 + 1].x);
        acc[ii * 4 + 1].y = fmaf(r.y, x.y, acc[ii * 4 + 1].y);
        acc[ii * 4 + 2].x = fmaf(r.z, x.x, acc[ii * 4 + 2].x);
        acc[ii * 4 + 2].y = fmaf(r.z, x.y, acc[ii * 4 + 2].y);
        acc[ii * 4 + 3].x = fmaf(r.w, x.x, acc[ii * 4 + 3].x);
        acc[ii * 4 + 3].y = fmaf(r.w, x.y, acc[ii * 4 + 3].y);
      }
    }

#pragma unroll
    for (int i = 0; i < N; ++i) {
      *(float2*)(out + (size_t)i * m + j) = acc[i];
    }
  } else {
    // tail: single column j (only if m is odd)
    float acc[N];
#pragma unroll
    for (int i = 0; i < N; ++i) acc[i] = 0.0f;

#pragma unroll 4
    for (int k = 0; k < N; ++k) {
      const float x = X[(size_t)k * m + j];
      const float4* r4 = (const float4*)(RT + k * N);
#pragma unroll
      for (int ii = 0; ii < N / 4; ++ii) {
        float4 r = r4[ii];
        acc[ii * 4 + 0] = fmaf(r.x, x, acc[ii * 4 + 0]);
        acc[ii * 4 + 1] = fmaf(r.y, x, acc[ii * 4 + 1]);
        acc[ii * 4 + 2] = fmaf(r.z, x, acc[ii * 4 + 2]);
        acc[ii * 4 + 3] = fmaf(r.w, x, acc[ii * 4 + 3]);
      }
    }

#pragma unroll
    for (int i = 0; i < N; ++i) {
      out[(size_t)i * m + j] = acc[i];
    }
  }
}

extern "C" void kernel_launch(void* const* d_in, const int* in_sizes, int n_in,
                              void* d_out, int out_size, void* d_ws,
                              size_t ws_size, hipStream_t stream) {
  const float* X = (const float*)d_in[0];       // 64 x m fp32
  const float* angles = (const float*)d_in[1];  // 2016 fp32
  const float* mus = (const float*)d_in[2];     // 64 fp32
  float* out = (float*)d_out;                   // 64 x m fp32
  float* RT = (float*)d_ws;                     // 64*64 fp32 scratch (16 KB)

  const int m = in_sizes[0] / N;

  build_r_kernel<<<1, 512, 0, stream>>>(angles, mus, RT);

  const int pairs = (m + 1) / 2;
  const int blocks = (pairs + 255) / 256;
  apply_r_kernel<<<blocks, 256, 0, stream>>>(X, RT, out, m);
}

// Round 3
// 477.638 us; speedup vs baseline: 1.4104x; 1.4104x over previous
//
#include <hip/hip_runtime.h>
#include <math.h>

// n is fixed by the problem: angles has n(n-1)/2 = 2016 -> n = 64.
#define N 64
#define NPAIRS (N * (N - 1) / 2)  // 2016
#define NSEG 8
#define SEGLEN (NPAIRS / NSEG)    // 252
#define STJ 68                    // padded stride (floats) for transposed segment tile

// Pairs before row t in np.triu_indices(64, k=1) row-major order.
constexpr int k0row(int t) { return t * 63 - t * (t - 1) / 2; }
// Row containing rotation index k.
constexpr int rowOf(int k) {
  int t = 0;
  while (t < 62 && k0row(t + 1) <= k) ++t;
  return t;
}

// ---------------------------------------------------------------------------
// Rotation chain [K, END) via template recursion: every col[]/cs[] index is a
// template literal, so col[] provably stays in VGPRs (no runtime indexing is
// even expressible here -- the round-1/2 unroll-failure mode is impossible).
// ---------------------------------------------------------------------------
template <int K, int END>
__device__ __forceinline__ void chain(float col[N], const float2* cs) {
  if constexpr (K < END) {
    constexpr int t = rowOf(K);
    constexpr int b = K - k0row(t) + t + 1;
    const float2 p = cs[K];  // wave-uniform LDS read -> broadcast
    const float rt = col[t];
    const float rb = col[b];
    col[t] = fmaf(p.x, rt, -p.y * rb);
    col[b] = fmaf(p.y, rt, p.x * rb);
    chain<K + 1, END>(col, cs);
  }
}

// ---------------------------------------------------------------------------
// Kernel 1: build R^T (scaled by mus) from the Givens angle sequence.
// 512 threads (8 waves), 1 block.
//   Phase 1: wave w computes segment product S_w = G_{(w+1)*252-1}..G_{w*252}
//            (one column per lane, in VGPRs, template-literal indices).
//   Phase 2: sequential combine P <- S_w * P for w = 1..7 using all 512
//            threads (validated correct in rounds 1-2).
// Output layout: RT[j*64 + i] = mus[i] * R[i][j].
// ---------------------------------------------------------------------------
__global__ __launch_bounds__(512) void build_r_kernel(
    const float* __restrict__ angles, const float* __restrict__ mus,
    float* __restrict__ RT) {
  __shared__ float2 cs[NPAIRS];   // 16128 B
  __shared__ float P[N * N];      // running product, P[k*64 + j]   (16384 B)
  __shared__ float ST[N * STJ];   // S_w transposed: ST[k*STJ + i]  (17408 B)

  const int tid = threadIdx.x;
  const int lane = tid & 63;
  const int wid = tid >> 6;

  // Parallel sincos across all 512 threads.
  for (int k = tid; k < NPAIRS; k += 512) {
    float s, c;
    sincosf(angles[k], &s, &c);
    cs[k] = make_float2(c, s);
  }
  __syncthreads();

  // ---- Phase 1: per-wave segment product, one column per lane ----
  float col[N];
#pragma unroll
  for (int i = 0; i < N; ++i) col[i] = (i == lane) ? 1.0f : 0.0f;

  switch (wid) {
    case 0: chain<0 * SEGLEN, 1 * SEGLEN>(col, cs); break;
    case 1: chain<1 * SEGLEN, 2 * SEGLEN>(col, cs); break;
    case 2: chain<2 * SEGLEN, 3 * SEGLEN>(col, cs); break;
    case 3: chain<3 * SEGLEN, 4 * SEGLEN>(col, cs); break;
    case 4: chain<4 * SEGLEN, 5 * SEGLEN>(col, cs); break;
    case 5: chain<5 * SEGLEN, 6 * SEGLEN>(col, cs); break;
    case 6: chain<6 * SEGLEN, 7 * SEGLEN>(col, cs); break;
    case 7: chain<7 * SEGLEN, 8 * SEGLEN>(col, cs); break;
  }

  // ---- Phase 2: P <- S_0, then P <- S_w * P for w = 1..7 ----
  if (wid == 0) {
#pragma unroll
    for (int i = 0; i < N; ++i) P[i * N + lane] = col[i];  // stride-1: conflict-free
  }
  __syncthreads();

  const int i0 = wid * 8;
  float acc[8];
#pragma unroll
  for (int u = 0; u < 8; ++u) acc[u] = 0.0f;

  for (int w = 1; w < NSEG; ++w) {
    // Wave w dumps its segment, transposed: ST[k][i] = S_w[i][k].
    if (wid == w) {
#pragma unroll
      for (int u = 0; u < N / 4; ++u) {
        *(float4*)&ST[lane * STJ + u * 4] =
            make_float4(col[4 * u], col[4 * u + 1], col[4 * u + 2], col[4 * u + 3]);
      }
    }
    __syncthreads();

    // C = S_w * P ; thread computes C[i0..i0+8)[lane].
#pragma unroll
    for (int u = 0; u < 8; ++u) acc[u] = 0.0f;
#pragma unroll 4
    for (int k = 0; k < N; ++k) {
      float bkj = P[k * N + lane];                        // stride-1: conflict-free
      float4 a0 = *(const float4*)&ST[k * STJ + i0];      // uniform: broadcast
      float4 a1 = *(const float4*)&ST[k * STJ + i0 + 4];  // uniform: broadcast
      acc[0] = fmaf(a0.x, bkj, acc[0]);
      acc[1] = fmaf(a0.y, bkj, acc[1]);
      acc[2] = fmaf(a0.z, bkj, acc[2]);
      acc[3] = fmaf(a0.w, bkj, acc[3]);
      acc[4] = fmaf(a1.x, bkj, acc[4]);
      acc[5] = fmaf(a1.y, bkj, acc[5]);
      acc[6] = fmaf(a1.z, bkj, acc[6]);
      acc[7] = fmaf(a1.w, bkj, acc[7]);
    }
    __syncthreads();
#pragma unroll
    for (int u = 0; u < 8; ++u) P[(i0 + u) * N + lane] = acc[u];
    __syncthreads();
  }

  // acc holds final R rows [i0, i0+8) of column `lane`.
  // RT[j][i] = mus[i] * R[i][j]
#pragma unroll
  for (int u = 0; u < 8; ++u) {
    const int i = i0 + u;
    RT[lane * N + i] = mus[i] * acc[u];
  }
}

// ---------------------------------------------------------------------------
// Kernel 2: out[i][j] = sum_k R[i][k] * X[k][j].
// ONE column j per thread (round-0 proven structure: VGPR ~68, no spill).
// RT reads are wave-uniform global loads -> scalar s_load (free pipe).
// X loads / out stores: nontemporal (each byte touched exactly once;
// round 1 measured WRITE_SIZE = 250 MB ideal with NT stores).
// ---------------------------------------------------------------------------
__global__ __launch_bounds__(256) void apply_r_kernel(
    const float* __restrict__ X, const float* __restrict__ RT,
    float* __restrict__ out, int m) {
  const int j = blockIdx.x * 256 + threadIdx.x;
  if (j >= m) return;

  float acc[N];
#pragma unroll
  for (int i = 0; i < N; ++i) acc[i] = 0.0f;

  const float* xp = X + j;
#pragma unroll 4
  for (int k = 0; k < N; ++k) {
    const float x = __builtin_nontemporal_load(xp + (size_t)k * m);
    const float4* r4 = (const float4*)(RT + k * N);
#pragma unroll
    for (int ii = 0; ii < N / 4; ++ii) {
      float4 r = r4[ii];
      acc[ii * 4 + 0] = fmaf(r.x, x, acc[ii * 4 + 0]);
      acc[ii * 4 + 1] = fmaf(r.y, x, acc[ii * 4 + 1]);
      acc[ii * 4 + 2] = fmaf(r.z, x, acc[ii * 4 + 2]);
      acc[ii * 4 + 3] = fmaf(r.w, x, acc[ii * 4 + 3]);
    }
  }

#pragma unroll
  for (int i = 0; i < N; ++i) {
    __builtin_nontemporal_store(acc[i], out + (size_t)i * m + j);
  }
}

extern "C" void kernel_launch(void* const* d_in, const int* in_sizes, int n_in,
                              void* d_out, int out_size, void* d_ws,
                              size_t ws_size, hipStream_t stream) {
  const float* X = (const float*)d_in[0];       // 64 x m fp32
  const float* angles = (const float*)d_in[1];  // 2016 fp32
  const float* mus = (const float*)d_in[2];     // 64 fp32
  float* out = (float*)d_out;                   // 64 x m fp32
  float* RT = (float*)d_ws;                     // 64*64 fp32 scratch (16 KB)

  const int m = in_sizes[0] / N;

  build_r_kernel<<<1, 512, 0, stream>>>(angles, mus, RT);

  const int blocks = (m + 255) / 256;
  apply_r_kernel<<<blocks, 256, 0, stream>>>(X, RT, out, m);
}